// Round 1
// baseline (1425.002 us; speedup 1.0000x reference)
//
#include <hip/hip_runtime.h>
#include <hip/hip_bf16.h>

#define N_ANCH 100800
#define BATCH 64
#define KTOP 512

// ---------------------------------------------------------------------------
// K0: zero the per-image candidate counters (ws is poisoned 0xAA each call)
// ---------------------------------------------------------------------------
__global__ void zero_cnt_kernel(int* __restrict__ cnt) {
    if (threadIdx.x < BATCH) cnt[threadIdx.x] = 0;
}

// ---------------------------------------------------------------------------
// K1: filter — score = p4*p5 > 0.7, compact (score_bits<<32 | ~idx) keys into
// per-image candidate lists. LDS-staged float4 loads for full coalescing.
// grid = (ceil(N/256), B), block = 256.
// ---------------------------------------------------------------------------
__global__ void filter_kernel(const float* __restrict__ pred,
                              unsigned long long* __restrict__ cand,
                              int* __restrict__ cnt, int cap) {
    __shared__ float tile[256 * 9];

    const int b  = blockIdx.y;
    const int r0 = blockIdx.x * 256;
    const int rows = min(256, N_ANCH - r0);
    const size_t base = ((size_t)b * N_ANCH + r0) * 9;   // divisible by 4 -> 16B aligned

    const int nf4 = (rows * 9) >> 2;                     // rows*9 divisible by 4 (256*9, 160*9)
    const float4* __restrict__ src = (const float4*)(pred + base);
    float4* dst4 = (float4*)tile;
    for (int f = threadIdx.x; f < nf4; f += 256) dst4[f] = src[f];
    __syncthreads();

    const int t = threadIdx.x;
    bool has = false;
    unsigned long long key = 0;
    if (t < rows) {
        float s = tile[t * 9 + 4] * tile[t * 9 + 5];
        if (s > 0.7f) {
            has = true;
            unsigned int sb = __float_as_uint(s);
            unsigned int gi = (unsigned int)(r0 + t);
            key = ((unsigned long long)sb << 32) | (unsigned long long)(~gi);
        }
    }

    // wave-aggregated atomic append
    unsigned long long m = __ballot(has);
    if (m) {
        int lane   = threadIdx.x & 63;
        int nact   = __popcll(m);
        int leader = __ffsll((unsigned long long)m) - 1;
        int basep  = 0;
        if (lane == leader) basep = atomicAdd(&cnt[b], nact);
        basep = __shfl(basep, leader);
        if (has) {
            int rank = __popcll(m & ((1ull << lane) - 1ull));
            int pos  = basep + rank;
            if (pos < cap) cand[(size_t)b * cap + pos] = key;
        }
    }
}

// ---------------------------------------------------------------------------
// K2: per-image top-512 select (histogram + bitonic), pairwise-IoU bitmask,
// greedy serial suppression, output write. grid = B, block = 256.
// ---------------------------------------------------------------------------
__global__ void nms_kernel(const float* __restrict__ pred,
                           const unsigned long long* __restrict__ cand,
                           const int* __restrict__ cnt,
                           float* __restrict__ out, int cap) {
#pragma clang fp contract(off)
    __shared__ int hist[2048];
    __shared__ unsigned long long sel[1024];
    __shared__ float4 boxes[KTOP];
    __shared__ float sc[KTOP];
    __shared__ int ids[KTOP];
    __shared__ unsigned long long msk[KTOP][8];
    __shared__ unsigned long long rmw[8];
    __shared__ int s_bstar, s_nsel;

    const int b = blockIdx.x;
    const int t = threadIdx.x;
    const int c = min(cnt[b], cap);
    const unsigned long long* __restrict__ cb = cand + (size_t)b * cap;

    for (int i = t; i < 2048; i += 256) hist[i] = 0;
    for (int i = t; i < 1024; i += 256) sel[i] = 0;
    if (t == 0) s_nsel = 0;
    __syncthreads();

    // --- histogram over score mantissa bits (monotonic bucket in [0.7,1)) ---
    for (int i = t; i < c; i += 256) {
        unsigned int sb = (unsigned int)(cb[i] >> 32);
        atomicAdd(&hist[(sb >> 12) & 0x7FF], 1);
    }
    __syncthreads();

    if (t == 0) {
        int cum = 0, bstar = 0;
        for (int k = 2047; k >= 0; --k) {
            cum += hist[k];
            if (cum >= KTOP) { bstar = k; break; }
        }
        s_bstar = bstar;   // if total < 512, stays 0 -> select everything
    }
    __syncthreads();

    // --- compact candidates in buckets >= bstar (~516 expected) ---
    const int bstar = s_bstar;
    for (int i = t; i < c; i += 256) {
        unsigned long long k = cb[i];
        unsigned int sb = (unsigned int)(k >> 32);
        if ((int)((sb >> 12) & 0x7FF) >= bstar) {
            int p = atomicAdd(&s_nsel, 1);
            if (p < 1024) sel[p] = k;
        }
    }
    __syncthreads();
    const int v = min(s_nsel, KTOP);

    // --- bitonic sort, 1024 keys, descending (key = score_bits<<32 | ~idx) ---
    for (int k = 2; k <= 1024; k <<= 1) {
        for (int j = k >> 1; j > 0; j >>= 1) {
            __syncthreads();
            for (int p = t; p < 512; p += 256) {
                int i0 = ((p & ~(j - 1)) << 1) | (p & (j - 1));
                int i1 = i0 | j;
                unsigned long long a = sel[i0], bb = sel[i1];
                bool up = ((i0 & k) == 0);          // up: larger key first
                if ((a < bb) == up) { sel[i0] = bb; sel[i1] = a; }
            }
        }
    }
    __syncthreads();

    // --- gather top-512 rows, xywh -> xyxy ---
    for (int s = t; s < KTOP; s += 256) {
        float4 bx = make_float4(0.f, 0.f, 0.f, 0.f);
        float scv = 0.f;
        int gid = -1;
        if (s < v) {
            unsigned long long k = sel[s];
            scv = __uint_as_float((unsigned int)(k >> 32));
            gid = (int)(~(unsigned int)(k & 0xFFFFFFFFull));
            const float* row = pred + ((size_t)b * N_ANCH + gid) * 9;
            float cx = row[0], cy = row[1], w = row[2], h = row[3];
            float hw = w * 0.5f, hh = h * 0.5f;   // exact halving
            bx = make_float4(cx - hw, cy - hh, cx + hw, cy + hh);
        }
        boxes[s] = bx;
        sc[s] = scv;
        ids[s] = gid;
    }
    __syncthreads();

    // --- IoU bitmask: msk[i][w] bit jj set iff IoU(i, w*64+jj) > 0.45, j > i ---
    for (int kk = 0; kk < 16; ++kk) {
        int i = t + ((kk & 1) << 8);   // 0..511 (wave-uniform j loop below)
        int w = kk >> 1;
        unsigned long long mword = 0;
        float4 bi = boxes[i];
        float ai = (bi.z - bi.x) * (bi.w - bi.y);
        int j0 = w << 6;
        if (j0 + 63 > i) {
            for (int jj = 0; jj < 64; ++jj) {
                int j = j0 + jj;
                if (j > i) {
                    float4 bj = boxes[j];
                    float xx1 = fmaxf(bi.x, bj.x);
                    float yy1 = fmaxf(bi.y, bj.y);
                    float xx2 = fminf(bi.z, bj.z);
                    float yy2 = fminf(bi.w, bj.w);
                    float ww = fmaxf(xx2 - xx1, 0.f);
                    float hh = fmaxf(yy2 - yy1, 0.f);
                    float inter = ww * hh;
                    float aj = (bj.z - bj.x) * (bj.w - bj.y);
                    float uni = ai + aj - inter;
                    float iou = inter / (uni + 1e-7f);
                    if (iou > 0.45f) mword |= (1ull << jj);
                }
            }
        }
        msk[i][w] = mword;
    }
    __syncthreads();

    // --- greedy serial scan (registers on thread 0) ---
    if (t == 0) {
        unsigned long long rm[8] = {0, 0, 0, 0, 0, 0, 0, 0};
        for (int i = 0; i < KTOP; ++i) {
            if (!((rm[i >> 6] >> (i & 63)) & 1ull) && sc[i] > 0.7f) {
                rm[0] |= msk[i][0]; rm[1] |= msk[i][1];
                rm[2] |= msk[i][2]; rm[3] |= msk[i][3];
                rm[4] |= msk[i][4]; rm[5] |= msk[i][5];
                rm[6] |= msk[i][6]; rm[7] |= msk[i][7];
            }
        }
        for (int w = 0; w < 8; ++w) rmw[w] = rm[w];
    }
    __syncthreads();

    // --- output: [x1,y1,x2,y2,conf,0,pitch,yaw,roll] or zeros ---
    for (int s = t; s < KTOP; s += 256) {
        float* o = out + ((size_t)b * KTOP + s) * 9;
        bool keep = (sc[s] > 0.7f) && !((rmw[s >> 6] >> (s & 63)) & 1ull);
        if (keep) {
            float4 bx = boxes[s];
            const float* row = pred + ((size_t)b * N_ANCH + ids[s]) * 9;
            o[0] = bx.x; o[1] = bx.y; o[2] = bx.z; o[3] = bx.w;
            o[4] = sc[s]; o[5] = 0.f;
            o[6] = row[6]; o[7] = row[7]; o[8] = row[8];
        } else {
            o[0] = 0.f; o[1] = 0.f; o[2] = 0.f; o[3] = 0.f;
            o[4] = 0.f; o[5] = 0.f; o[6] = 0.f; o[7] = 0.f; o[8] = 0.f;
        }
    }
}

// ---------------------------------------------------------------------------
extern "C" void kernel_launch(void* const* d_in, const int* in_sizes, int n_in,
                              void* d_out, int out_size, void* d_ws, size_t ws_size,
                              hipStream_t stream) {
    const float* pred = (const float*)d_in[0];
    float* out = (float*)d_out;

    int* cnt = (int*)d_ws;
    unsigned long long* cand = (unsigned long long*)((char*)d_ws + 4096);

    int cap = 8192;   // mean candidates/image ~5073, sigma ~69 -> 45-sigma headroom
    size_t need = 4096 + (size_t)BATCH * cap * sizeof(unsigned long long);
    if (ws_size < need) {
        cap = (int)((ws_size > 4096 ? (ws_size - 4096) : 0) / (BATCH * sizeof(unsigned long long)));
    }

    zero_cnt_kernel<<<1, 64, 0, stream>>>(cnt);

    dim3 g1((N_ANCH + 255) / 256, BATCH);
    filter_kernel<<<g1, 256, 0, stream>>>(pred, cand, cnt, cap);

    nms_kernel<<<BATCH, 256, 0, stream>>>(pred, cand, cnt, out, cap);
}

// Round 2
// 480.089 us; speedup vs baseline: 2.9682x; 2.9682x over previous
//
#include <hip/hip_runtime.h>
#include <hip/hip_bf16.h>

#define N_ANCH 100800
#define BATCH 64
#define KTOP 512
#define CNT_STRIDE 64   // pad counters to 256 B so each lives on its own L2 line

// ---------------------------------------------------------------------------
// K0: zero the per-image candidate counters (ws is poisoned 0xAA each call)
// ---------------------------------------------------------------------------
__global__ void zero_cnt_kernel(int* __restrict__ cnt) {
    if (threadIdx.x < BATCH) cnt[threadIdx.x * CNT_STRIDE] = 0;
}

// ---------------------------------------------------------------------------
// K1: filter — score = p4*p5 > 0.7, compact (score_bits<<32 | ~idx) keys into
// per-image candidate lists. LDS-staged float4 loads for full coalescing.
// ONE global atomic per block (LDS-aggregated) onto a 256B-padded counter:
// R1 showed per-wave atomics to packed counters serialize (~1ms!).
// grid = (ceil(N/256), B), block = 256.
// ---------------------------------------------------------------------------
__global__ void filter_kernel(const float* __restrict__ pred,
                              unsigned long long* __restrict__ cand,
                              int* __restrict__ cnt, int cap) {
    __shared__ float tile[256 * 9];
    __shared__ int s_wbase[4];
    __shared__ int s_blkcnt;
    __shared__ int s_gbase;

    const int b  = blockIdx.y;
    const int r0 = blockIdx.x * 256;
    const int rows = min(256, N_ANCH - r0);
    const size_t base = ((size_t)b * N_ANCH + r0) * 9;   // divisible by 4 -> 16B aligned

    if (threadIdx.x == 0) s_blkcnt = 0;

    const int nf4 = (rows * 9) >> 2;                     // rows divisible by 4 here
    const float4* __restrict__ src = (const float4*)(pred + base);
    float4* dst4 = (float4*)tile;
    for (int f = threadIdx.x; f < nf4; f += 256) dst4[f] = src[f];
    __syncthreads();

    const int t = threadIdx.x;
    const int wid = t >> 6, lane = t & 63;
    bool has = false;
    unsigned long long key = 0;
    if (t < rows) {
        float s = tile[t * 9 + 4] * tile[t * 9 + 5];
        if (s > 0.7f) {
            has = true;
            unsigned int sb = __float_as_uint(s);
            unsigned int gi = (unsigned int)(r0 + t);
            key = ((unsigned long long)sb << 32) | (unsigned long long)(~gi);
        }
    }

    unsigned long long m = __ballot(has);               // all threads reach here
    if (lane == 0) s_wbase[wid] = atomicAdd(&s_blkcnt, __popcll(m));
    __syncthreads();
    if (t == 0) s_gbase = atomicAdd(&cnt[b * CNT_STRIDE], s_blkcnt);
    __syncthreads();

    if (has) {
        int rank = __popcll(m & ((1ull << lane) - 1ull));
        int pos = s_gbase + s_wbase[wid] + rank;
        if (pos < cap) cand[(size_t)b * cap + pos] = key;
    }
}

// ---------------------------------------------------------------------------
// K2: per-image top-512 select (histogram + bitonic), pairwise-IoU bitmask,
// greedy suppression (ffs over kept boxes only), output write.
// grid = B, block = 256.
// ---------------------------------------------------------------------------
__global__ void nms_kernel(const float* __restrict__ pred,
                           const unsigned long long* __restrict__ cand,
                           const int* __restrict__ cnt,
                           float* __restrict__ out, int cap) {
#pragma clang fp contract(off)
    __shared__ int hist[2048];
    __shared__ int csf[256];
    __shared__ unsigned long long sel[1024];
    __shared__ float4 boxes[KTOP];
    __shared__ float sc[KTOP];
    __shared__ int ids[KTOP];
    __shared__ unsigned long long msk[KTOP][8];
    __shared__ unsigned long long rmw[8];
    __shared__ int s_bstar, s_nsel;

    const int b = blockIdx.x;
    const int t = threadIdx.x;
    const int c = min(cnt[b * CNT_STRIDE], cap);
    const unsigned long long* __restrict__ cb = cand + (size_t)b * cap;

    for (int i = t; i < 2048; i += 256) hist[i] = 0;
    for (int i = t; i < 1024; i += 256) sel[i] = 0;
    if (t == 0) { s_nsel = 0; s_bstar = 0; }
    __syncthreads();

    // --- histogram over score mantissa bits (monotonic bucket in [0.7,1)) ---
    for (int i = t; i < c; i += 256) {
        unsigned int sb = (unsigned int)(cb[i] >> 32);
        atomicAdd(&hist[(sb >> 12) & 0x7FF], 1);
    }
    __syncthreads();

    // --- two-level parallel suffix scan to find cut bucket bstar ---
    {
        int s = 0;
        #pragma unroll
        for (int j = 0; j < 8; ++j) s += hist[t * 8 + j];
        csf[t] = s;
        __syncthreads();
        for (int off = 1; off < 256; off <<= 1) {
            int v2 = csf[t] + ((t + off < 256) ? csf[t + off] : 0);
            __syncthreads();
            csf[t] = v2;
            __syncthreads();
        }
        // csf[t] = count of candidates in buckets >= t*8
        int cs_t  = csf[t];
        int cs_t1 = (t == 255) ? 0 : csf[t + 1];
        if (cs_t >= KTOP && cs_t1 < KTOP) {       // crossing chunk (at most one t)
            int cum = cs_t1, bstar = t * 8;
            for (int j = 7; j >= 0; --j) {
                cum += hist[t * 8 + j];
                if (cum >= KTOP) { bstar = t * 8 + j; break; }
            }
            s_bstar = bstar;
        }
        __syncthreads();
    }

    // --- compact candidates in buckets >= bstar (~520 expected) ---
    const int bstar = s_bstar;
    for (int i = t; i < c; i += 256) {
        unsigned long long k = cb[i];
        unsigned int sb = (unsigned int)(k >> 32);
        if ((int)((sb >> 12) & 0x7FF) >= bstar) {
            int p = atomicAdd(&s_nsel, 1);
            if (p < 1024) sel[p] = k;
        }
    }
    __syncthreads();
    const int v = min(s_nsel, KTOP);

    // --- bitonic sort, 1024 keys, descending (key = score_bits<<32 | ~idx) ---
    for (int k = 2; k <= 1024; k <<= 1) {
        for (int j = k >> 1; j > 0; j >>= 1) {
            __syncthreads();
            for (int p = t; p < 512; p += 256) {
                int i0 = ((p & ~(j - 1)) << 1) | (p & (j - 1));
                int i1 = i0 | j;
                unsigned long long a = sel[i0], bb = sel[i1];
                bool up = ((i0 & k) == 0);          // up: larger key first
                if ((a < bb) == up) { sel[i0] = bb; sel[i1] = a; }
            }
        }
    }
    __syncthreads();

    // --- gather top-512 rows, xywh -> xyxy ---
    for (int s = t; s < KTOP; s += 256) {
        float4 bx = make_float4(0.f, 0.f, 0.f, 0.f);
        float scv = 0.f;
        int gid = -1;
        if (s < v) {
            unsigned long long k = sel[s];
            scv = __uint_as_float((unsigned int)(k >> 32));
            gid = (int)(~(unsigned int)(k & 0xFFFFFFFFull));
            const float* row = pred + ((size_t)b * N_ANCH + gid) * 9;
            float cx = row[0], cy = row[1], w = row[2], h = row[3];
            float hw = w * 0.5f, hh = h * 0.5f;   // exact halving
            bx = make_float4(cx - hw, cy - hh, cx + hw, cy + hh);
        }
        boxes[s] = bx;
        sc[s] = scv;
        ids[s] = gid;
    }
    __syncthreads();

    // --- IoU bitmask: msk[i][w] bit jj set iff IoU(i, w*64+jj) > 0.45, j > i ---
    for (int kk = 0; kk < 16; ++kk) {
        int i = t + ((kk & 1) << 8);   // 0..511
        int w = kk >> 1;
        unsigned long long mword = 0;
        float4 bi = boxes[i];
        float ai = (bi.z - bi.x) * (bi.w - bi.y);
        int j0 = w << 6;
        if (j0 + 63 > i) {
            for (int jj = 0; jj < 64; ++jj) {
                int j = j0 + jj;
                if (j > i) {
                    float4 bj = boxes[j];
                    float xx1 = fmaxf(bi.x, bj.x);
                    float yy1 = fmaxf(bi.y, bj.y);
                    float xx2 = fminf(bi.z, bj.z);
                    float yy2 = fminf(bi.w, bj.w);
                    float ww = fmaxf(xx2 - xx1, 0.f);
                    float hh = fmaxf(yy2 - yy1, 0.f);
                    float inter = ww * hh;
                    float aj = (bj.z - bj.x) * (bj.w - bj.y);
                    float uni = ai + aj - inter;
                    float iou = inter / (uni + 1e-7f);
                    if (iou > 0.45f) mword |= (1ull << jj);
                }
            }
        }
        msk[i][w] = mword;
    }
    __syncthreads();

    // --- greedy suppression: visit only kept boxes via ffs over alive mask ---
    if (t == 0) {
        unsigned long long rm[8] = {0, 0, 0, 0, 0, 0, 0, 0};
        for (int w = 0; w < 8 && (w << 6) < v; ++w) {
            int rem = v - (w << 6);
            unsigned long long valid = (rem >= 64) ? ~0ull : ((1ull << rem) - 1ull);
            unsigned long long alive = ~rm[w] & valid;
            while (alive) {
                int bit = __ffsll(alive) - 1;
                int i = (w << 6) + bit;
                #pragma unroll
                for (int u = 0; u < 8; ++u) rm[u] |= msk[i][u];
                alive &= ~rm[w];
                alive &= (bit == 63) ? 0ull : (~0ull << (bit + 1));
            }
        }
        #pragma unroll
        for (int u = 0; u < 8; ++u) rmw[u] = rm[u];
    }
    __syncthreads();

    // --- output: [x1,y1,x2,y2,conf,0,pitch,yaw,roll] or zeros ---
    for (int s = t; s < KTOP; s += 256) {
        float* o = out + ((size_t)b * KTOP + s) * 9;
        bool keep = (sc[s] > 0.7f) && !((rmw[s >> 6] >> (s & 63)) & 1ull);
        if (keep) {
            float4 bx = boxes[s];
            const float* row = pred + ((size_t)b * N_ANCH + ids[s]) * 9;
            o[0] = bx.x; o[1] = bx.y; o[2] = bx.z; o[3] = bx.w;
            o[4] = sc[s]; o[5] = 0.f;
            o[6] = row[6]; o[7] = row[7]; o[8] = row[8];
        } else {
            o[0] = 0.f; o[1] = 0.f; o[2] = 0.f; o[3] = 0.f;
            o[4] = 0.f; o[5] = 0.f; o[6] = 0.f; o[7] = 0.f; o[8] = 0.f;
        }
    }
}

// ---------------------------------------------------------------------------
extern "C" void kernel_launch(void* const* d_in, const int* in_sizes, int n_in,
                              void* d_out, int out_size, void* d_ws, size_t ws_size,
                              hipStream_t stream) {
    const float* pred = (const float*)d_in[0];
    float* out = (float*)d_out;

    int* cnt = (int*)d_ws;                                   // 64 counters, 256B stride
    unsigned long long* cand = (unsigned long long*)((char*)d_ws + BATCH * CNT_STRIDE * 4);

    int cap = 8192;   // mean candidates/image ~5073, sigma ~69 -> huge headroom
    size_t head = (size_t)BATCH * CNT_STRIDE * 4;
    size_t need = head + (size_t)BATCH * cap * sizeof(unsigned long long);
    if (ws_size < need) {
        cap = (int)((ws_size > head ? (ws_size - head) : 0) /
                    (BATCH * sizeof(unsigned long long)));
    }

    zero_cnt_kernel<<<1, 64, 0, stream>>>(cnt);

    dim3 g1((N_ANCH + 255) / 256, BATCH);
    filter_kernel<<<g1, 256, 0, stream>>>(pred, cand, cnt, cap);

    nms_kernel<<<BATCH, 256, 0, stream>>>(pred, cand, cnt, out, cap);
}

// Round 3
// 405.235 us; speedup vs baseline: 3.5165x; 1.1847x over previous
//
#include <hip/hip_runtime.h>
#include <hip/hip_bf16.h>

#define N_ANCH 100800
#define BATCH 64
#define KTOP 512
#define CNT_STRIDE 64   // pad counters to 256 B so each lives on its own L2 line

// ---------------------------------------------------------------------------
// K0: zero the per-image candidate counters (ws is poisoned 0xAA each call)
// ---------------------------------------------------------------------------
__global__ void zero_cnt_kernel(int* __restrict__ cnt) {
    if (threadIdx.x < BATCH) cnt[threadIdx.x * CNT_STRIDE] = 0;
}

// ---------------------------------------------------------------------------
// K1: filter — score = p4*p5 > 0.7, compact (score_bits<<32 | ~idx) keys into
// per-image candidate lists. LDS-staged float4 loads for full coalescing.
// ONE global atomic per block (LDS-aggregated) onto a 256B-padded counter.
// grid = (ceil(N/256), B), block = 256.
// ---------------------------------------------------------------------------
__global__ void filter_kernel(const float* __restrict__ pred,
                              unsigned long long* __restrict__ cand,
                              int* __restrict__ cnt, int cap) {
    __shared__ float tile[256 * 9];
    __shared__ int s_wbase[4];
    __shared__ int s_blkcnt;
    __shared__ int s_gbase;

    const int b  = blockIdx.y;
    const int r0 = blockIdx.x * 256;
    const int rows = min(256, N_ANCH - r0);
    const size_t base = ((size_t)b * N_ANCH + r0) * 9;   // divisible by 4 -> 16B aligned

    if (threadIdx.x == 0) s_blkcnt = 0;

    const int nf4 = (rows * 9) >> 2;                     // rows*9 divisible by 4 here
    const float4* __restrict__ src = (const float4*)(pred + base);
    float4* dst4 = (float4*)tile;
    for (int f = threadIdx.x; f < nf4; f += 256) dst4[f] = src[f];
    __syncthreads();

    const int t = threadIdx.x;
    const int wid = t >> 6, lane = t & 63;
    bool has = false;
    unsigned long long key = 0;
    if (t < rows) {
        float s = tile[t * 9 + 4] * tile[t * 9 + 5];
        if (s > 0.7f) {
            has = true;
            unsigned int sb = __float_as_uint(s);
            unsigned int gi = (unsigned int)(r0 + t);
            key = ((unsigned long long)sb << 32) | (unsigned long long)(~gi);
        }
    }

    unsigned long long m = __ballot(has);               // all threads reach here
    if (lane == 0) s_wbase[wid] = atomicAdd(&s_blkcnt, __popcll(m));
    __syncthreads();
    if (t == 0) s_gbase = atomicAdd(&cnt[b * CNT_STRIDE], s_blkcnt);
    __syncthreads();

    if (has) {
        int rank = __popcll(m & ((1ull << lane) - 1ull));
        int pos = s_gbase + s_wbase[wid] + rank;
        if (pos < cap) cand[(size_t)b * cap + pos] = key;
    }
}

// ---------------------------------------------------------------------------
// K2: per-image top-512 select (histogram + bitonic), pairwise-IoU bitmask,
// greedy suppression, output write. grid = B, block = 1024 (16 waves for
// latency hiding — R2 showed 4 waves/CU left the kernel latency-bound).
// ---------------------------------------------------------------------------
__global__ void __launch_bounds__(1024)
nms_kernel(const float* __restrict__ pred,
           const unsigned long long* __restrict__ cand,
           const int* __restrict__ cnt,
           float* __restrict__ out, int cap) {
#pragma clang fp contract(off)
    __shared__ int hist[2048];
    __shared__ int csf[256];
    __shared__ unsigned long long sel[1024];
    __shared__ float4 boxes[KTOP];
    __shared__ float sc[KTOP];
    __shared__ int ids[KTOP];
    __shared__ unsigned long long msk[KTOP][8];
    __shared__ unsigned long long rmw[8];
    __shared__ int s_bstar, s_nsel;

    const int b = blockIdx.x;
    const int t = threadIdx.x;
    const int c = min(cnt[b * CNT_STRIDE], cap);
    const unsigned long long* __restrict__ cb = cand + (size_t)b * cap;

    for (int i = t; i < 2048; i += 1024) hist[i] = 0;
    sel[t] = 0;
    if (t == 0) { s_nsel = 0; s_bstar = 0; }
    __syncthreads();

    // --- histogram over score mantissa bits (monotonic bucket in [0.7,1)) ---
    for (int i = t; i < c; i += 1024) {
        unsigned int sb = (unsigned int)(cb[i] >> 32);
        atomicAdd(&hist[(sb >> 12) & 0x7FF], 1);
    }
    __syncthreads();

    // --- two-level parallel suffix scan to find cut bucket bstar ---
    {
        if (t < 256) {
            int s = 0;
            #pragma unroll
            for (int j = 0; j < 8; ++j) s += hist[t * 8 + j];
            csf[t] = s;
        }
        __syncthreads();
        for (int off = 1; off < 256; off <<= 1) {
            int v2 = 0;
            if (t < 256) v2 = csf[t] + ((t + off < 256) ? csf[t + off] : 0);
            __syncthreads();
            if (t < 256) csf[t] = v2;
            __syncthreads();
        }
        // csf[t] = count of candidates in buckets >= t*8
        if (t < 256) {
            int cs_t  = csf[t];
            int cs_t1 = (t == 255) ? 0 : csf[t + 1];
            if (cs_t >= KTOP && cs_t1 < KTOP) {    // crossing chunk (at most one t)
                int cum = cs_t1, bstar = t * 8;
                for (int j = 7; j >= 0; --j) {
                    cum += hist[t * 8 + j];
                    if (cum >= KTOP) { bstar = t * 8 + j; break; }
                }
                s_bstar = bstar;
            }
        }
        __syncthreads();
    }

    // --- compact candidates in buckets >= bstar (~520 expected) ---
    const int bstar = s_bstar;
    for (int i = t; i < c; i += 1024) {
        unsigned long long k = cb[i];
        unsigned int sb = (unsigned int)(k >> 32);
        if ((int)((sb >> 12) & 0x7FF) >= bstar) {
            int p = atomicAdd(&s_nsel, 1);
            if (p < 1024) sel[p] = k;
        }
    }
    __syncthreads();
    const int v = min(s_nsel, KTOP);

    // --- bitonic sort, 1024 keys, descending (key = score_bits<<32 | ~idx) ---
    for (int k = 2; k <= 1024; k <<= 1) {
        for (int j = k >> 1; j > 0; j >>= 1) {
            __syncthreads();
            if (t < 512) {
                int i0 = ((t & ~(j - 1)) << 1) | (t & (j - 1));
                int i1 = i0 | j;
                unsigned long long a = sel[i0], bb = sel[i1];
                bool up = ((i0 & k) == 0);          // up: larger key first
                if ((a < bb) == up) { sel[i0] = bb; sel[i1] = a; }
            }
        }
    }
    __syncthreads();

    // --- gather top-512 rows, xywh -> xyxy ---
    if (t < KTOP) {
        int s = t;
        float4 bx = make_float4(0.f, 0.f, 0.f, 0.f);
        float scv = 0.f;
        int gid = -1;
        if (s < v) {
            unsigned long long k = sel[s];
            scv = __uint_as_float((unsigned int)(k >> 32));
            gid = (int)(~(unsigned int)(k & 0xFFFFFFFFull));
            const float* row = pred + ((size_t)b * N_ANCH + gid) * 9;
            float cx = row[0], cy = row[1], w = row[2], h = row[3];
            float hw = w * 0.5f, hh = h * 0.5f;   // exact halving
            bx = make_float4(cx - hw, cy - hh, cx + hw, cy + hh);
        }
        boxes[s] = bx;
        sc[s] = scv;
        ids[s] = gid;
    }
    __syncthreads();

    // --- IoU bitmask: msk[i][w] bit jj set iff IoU(i, w*64+jj) > 0.45, j > i.
    // Each thread owns (i = t&511) and 4 of the 8 mask words. Inner loop is
    // branch-free (mask j<=i bits after) + unrolled for ds_read ILP.
    {
        const int i = t & 511;
        const int wb = (t >> 9) << 2;   // 0 or 4
        float4 bi = boxes[i];
        float ai = (bi.z - bi.x) * (bi.w - bi.y);
        #pragma unroll
        for (int kk = 0; kk < 4; ++kk) {
            int w = wb + kk;
            int j0 = w << 6;
            unsigned long long mword = 0;
            if (j0 + 63 > i) {          // strip has at least one j > i
                #pragma unroll 8
                for (int jj = 0; jj < 64; ++jj) {
                    float4 bj = boxes[j0 + jj];
                    float xx1 = fmaxf(bi.x, bj.x);
                    float yy1 = fmaxf(bi.y, bj.y);
                    float xx2 = fminf(bi.z, bj.z);
                    float yy2 = fminf(bi.w, bj.w);
                    float ww = fmaxf(xx2 - xx1, 0.f);
                    float hh = fmaxf(yy2 - yy1, 0.f);
                    float inter = ww * hh;
                    float aj = (bj.z - bj.x) * (bj.w - bj.y);
                    float uni = ai + aj - inter;
                    float iou = inter / (uni + 1e-7f);
                    mword |= (unsigned long long)(iou > 0.45f) << jj;
                }
                if (j0 <= i) mword &= (~0ull) << (i - j0 + 1);  // keep only j > i
            }
            msk[i][w] = mword;
        }
    }
    __syncthreads();

    // --- greedy suppression: visit only kept boxes via ffs over alive mask ---
    if (t == 0) {
        unsigned long long rm[8] = {0, 0, 0, 0, 0, 0, 0, 0};
        for (int w = 0; w < 8 && (w << 6) < v; ++w) {
            int rem = v - (w << 6);
            unsigned long long valid = (rem >= 64) ? ~0ull : ((1ull << rem) - 1ull);
            unsigned long long alive = ~rm[w] & valid;
            while (alive) {
                int bit = __ffsll(alive) - 1;
                int i = (w << 6) + bit;
                #pragma unroll
                for (int u = 0; u < 8; ++u) rm[u] |= msk[i][u];
                alive &= ~rm[w];
                alive &= (bit == 63) ? 0ull : (~0ull << (bit + 1));
            }
        }
        #pragma unroll
        for (int u = 0; u < 8; ++u) rmw[u] = rm[u];
    }
    __syncthreads();

    // --- output: [x1,y1,x2,y2,conf,0,pitch,yaw,roll] or zeros ---
    if (t < KTOP) {
        int s = t;
        float* o = out + ((size_t)b * KTOP + s) * 9;
        bool keep = (sc[s] > 0.7f) && !((rmw[s >> 6] >> (s & 63)) & 1ull);
        if (keep) {
            float4 bx = boxes[s];
            const float* row = pred + ((size_t)b * N_ANCH + ids[s]) * 9;
            o[0] = bx.x; o[1] = bx.y; o[2] = bx.z; o[3] = bx.w;
            o[4] = sc[s]; o[5] = 0.f;
            o[6] = row[6]; o[7] = row[7]; o[8] = row[8];
        } else {
            o[0] = 0.f; o[1] = 0.f; o[2] = 0.f; o[3] = 0.f;
            o[4] = 0.f; o[5] = 0.f; o[6] = 0.f; o[7] = 0.f; o[8] = 0.f;
        }
    }
}

// ---------------------------------------------------------------------------
extern "C" void kernel_launch(void* const* d_in, const int* in_sizes, int n_in,
                              void* d_out, int out_size, void* d_ws, size_t ws_size,
                              hipStream_t stream) {
    const float* pred = (const float*)d_in[0];
    float* out = (float*)d_out;

    int* cnt = (int*)d_ws;                                   // 64 counters, 256B stride
    unsigned long long* cand = (unsigned long long*)((char*)d_ws + BATCH * CNT_STRIDE * 4);

    int cap = 8192;   // mean candidates/image ~5073, sigma ~69 -> huge headroom
    size_t head = (size_t)BATCH * CNT_STRIDE * 4;
    size_t need = head + (size_t)BATCH * cap * sizeof(unsigned long long);
    if (ws_size < need) {
        cap = (int)((ws_size > head ? (ws_size - head) : 0) /
                    (BATCH * sizeof(unsigned long long)));
    }

    zero_cnt_kernel<<<1, 64, 0, stream>>>(cnt);

    dim3 g1((N_ANCH + 255) / 256, BATCH);
    filter_kernel<<<g1, 256, 0, stream>>>(pred, cand, cnt, cap);

    nms_kernel<<<BATCH, 1024, 0, stream>>>(pred, cand, cnt, out, cap);
}